// Round 3
// baseline (302.474 us; speedup 1.0000x reference)
//
#include <hip/hip_runtime.h>
#include <math.h>

#define BB  2
#define TT  2048
#define SSQ 2048
#define DD  1024
#define HH  16
#define DKK 64
#define MM  (BB*TT)      // 4096 rows of activations
#define NN  (HH*DKK)     // 1024 proj width

typedef __attribute__((ext_vector_type(8))) short short8;
typedef __attribute__((ext_vector_type(4))) float f32x4;
typedef __attribute__((ext_vector_type(2))) unsigned int uint2v;
typedef __attribute__((ext_vector_type(4))) unsigned int u32x4;

__device__ __forceinline__ short f2bf(float x) {
    unsigned u = __builtin_bit_cast(unsigned, x);
    unsigned r = (u + 0x7FFFu + ((u >> 16) & 1u)) >> 16;
    return (short)r;
}

// pack two f32 into a bf16x2 word by truncation
__device__ __forceinline__ unsigned pk2(float lo, float hi) {
    return (__builtin_bit_cast(unsigned, hi) & 0xFFFF0000u) |
           (__builtin_bit_cast(unsigned, lo) >> 16);
}

__device__ __forceinline__ void glds16(const void* g, void* l) {
    __builtin_amdgcn_global_load_lds(
        (const __attribute__((address_space(1))) void*)g,
        (__attribute__((address_space(3))) void*)l, 16, 0, 0);
}

// ---------------------------------------------------------------------------
// fp32 -> bf16 elementwise (query/key/value), grid (MM*DD/2048, 3)
// ---------------------------------------------------------------------------
__global__ __launch_bounds__(256)
void to_bf16_acts(const float* __restrict__ a0, const float* __restrict__ a1,
                  const float* __restrict__ a2,
                  short* __restrict__ o0, short* __restrict__ o1,
                  short* __restrict__ o2)
{
    int z = blockIdx.y;
    const float* in = (z == 0) ? a0 : (z == 1) ? a1 : a2;
    short* out = (z == 0) ? o0 : (z == 1) ? o1 : o2;
    size_t i0 = ((size_t)blockIdx.x * 256 + threadIdx.x) * 8;
    f32x4 f0 = *(const f32x4*)(in + i0);
    f32x4 f1 = *(const f32x4*)(in + i0 + 4);
    short8 v;
#pragma unroll
    for (int j = 0; j < 4; j++) v[j] = f2bf(f0[j]);
#pragma unroll
    for (int j = 0; j < 4; j++) v[4 + j] = f2bf(f1[j]);
    *(short8*)(out + i0) = v;
}

// ---------------------------------------------------------------------------
// Weight transpose+convert: fp32 [K=1024][N=1024] -> bf16 [N][K].
// grid (16,16,4): z picks which weight.
// ---------------------------------------------------------------------------
__global__ __launch_bounds__(256)
void wtrans(const float* __restrict__ w0, const float* __restrict__ w1,
            const float* __restrict__ w2, const float* __restrict__ w3,
            short* __restrict__ t0, short* __restrict__ t1,
            short* __restrict__ t2, short* __restrict__ t3)
{
    __shared__ float Ls[64][65];
    int z = blockIdx.z;
    const float* in = (z == 0) ? w0 : (z == 1) ? w1 : (z == 2) ? w2 : w3;
    short* out = (z == 0) ? t0 : (z == 1) ? t1 : (z == 2) ? t2 : t3;
    const int r0 = blockIdx.y * 64, c0 = blockIdx.x * 64;
    const int t = threadIdx.x;
    const int r = t >> 2, c4 = t & 3;

    const float* src = in + (size_t)(r0 + r) * DD + c0 + c4 * 16;
#pragma unroll
    for (int i = 0; i < 4; i++) {
        f32x4 f = *(const f32x4*)(src + i * 4);
#pragma unroll
        for (int j = 0; j < 4; j++) Ls[r][c4 * 16 + i * 4 + j] = f[j];
    }
    __syncthreads();

    short8 va, vb;
#pragma unroll
    for (int j = 0; j < 8; j++) va[j] = f2bf(Ls[c4 * 16 + j][r]);
#pragma unroll
    for (int j = 0; j < 8; j++) vb[j] = f2bf(Ls[c4 * 16 + 8 + j][r]);
    short* dst = out + (size_t)(c0 + r) * DD + r0 + c4 * 16;
    *(short8*)dst = va;
    *(short8*)(dst + 8) = vb;
}

// ---------------------------------------------------------------------------
// bf16 transpose: [bh][t][dk=64] -> [bh][dk][t]. grid (TT/64, BB*HH).
// ---------------------------------------------------------------------------
__global__ __launch_bounds__(256)
void vtrans(const short* __restrict__ in, short* __restrict__ out)
{
    __shared__ short Ls[64][72];
    const int bh = blockIdx.y;
    const int t0 = blockIdx.x * 64;
    const int tid = threadIdx.x;
    const int r = tid >> 2, c4 = tid & 3;

    const short* src = in + ((size_t)bh * TT + t0 + r) * DKK + c4 * 16;
    *(short8*)&Ls[r][c4 * 16]     = *(const short8*)(src);
    *(short8*)&Ls[r][c4 * 16 + 8] = *(const short8*)(src + 8);
    __syncthreads();

    short8 a, b;
#pragma unroll
    for (int j = 0; j < 8; j++) a[j] = Ls[c4 * 16 + j][r];
#pragma unroll
    for (int j = 0; j < 8; j++) b[j] = Ls[c4 * 16 + 8 + j][r];
    short* dst = out + ((size_t)bh * DKK + r) * SSQ + t0 + c4 * 16;
    *(short8*)dst = a;
    *(short8*)(dst + 8) = b;
}

// ---------------------------------------------------------------------------
// m97-style bf16 GEMM core: C128x128 = A[M][K] @ Bt[N][K]^T, BK=32,
// 256 thr = 4 waves (2x2), each wave 64x64 = 4x4 MFMA tiles.
// ---------------------------------------------------------------------------
__device__ __forceinline__ void gemm_core(const short* __restrict__ A,
                                          const short* __restrict__ Bt,
                                          int m0, int n0,
                                          short* As, short* Bs,
                                          f32x4 (&acc)[4][4])
{
    const int tid = threadIdx.x;
    const int w = tid >> 6, l = tid & 63;
    const int l15 = l & 15, quad = l >> 4;
    const int wm = w >> 1, wn = w & 1;

#pragma unroll
    for (int i = 0; i < 4; i++)
#pragma unroll
        for (int j = 0; j < 4; j++) acc[i][j] = (f32x4){0.f, 0.f, 0.f, 0.f};

    const int r = tid >> 2, cseg = tid & 3;
    const short* gA = A + (size_t)(m0 + r) * DD + cseg * 8;
    const short* gB = Bt + (size_t)(n0 + r) * DD + cseg * 8;
    short* ldsA = As + w * 512;
    short* ldsB = Bs + w * 512;

    for (int k0 = 0; k0 < DD; k0 += 32) {
        glds16(gA + k0,                 ldsA);
        glds16(gA + (size_t)64 * DD + k0, ldsA + 2048);
        glds16(gB + k0,                 ldsB);
        glds16(gB + (size_t)64 * DD + k0, ldsB + 2048);
        __syncthreads();

        short8 bF[4];
#pragma unroll
        for (int ni = 0; ni < 4; ni++)
            bF[ni] = *(const short8*)&Bs[(wn * 64 + ni * 16 + l15) * 32 + quad * 8];
#pragma unroll
        for (int mi = 0; mi < 4; mi++) {
            short8 aF = *(const short8*)&As[(wm * 64 + mi * 16 + l15) * 32 + quad * 8];
#pragma unroll
            for (int ni = 0; ni < 4; ni++)
                acc[mi][ni] = __builtin_amdgcn_mfma_f32_16x16x32_bf16(aF, bF[ni], acc[mi][ni], 0, 0, 0);
        }
        __syncthreads();
    }
}

// ---------------------------------------------------------------------------
// QKV projection GEMM. z picks {Q,K,V}. All outputs bf16 [bh][t][dk]
// (coalesced 32B-segment stores); V transposed later by vtrans.
// Q scaled by 1/sqrt(dk)*log2(e) so attention uses exp2.
// ---------------------------------------------------------------------------
__global__ __launch_bounds__(256, 3)
void gemm_qkv(const short* __restrict__ Aq, const short* __restrict__ Ak,
              const short* __restrict__ Av,
              const short* __restrict__ Wqt, const short* __restrict__ Wkt,
              const short* __restrict__ Wvt,
              const float* __restrict__ bq, const float* __restrict__ bk,
              const float* __restrict__ bv,
              short* __restrict__ Qb, short* __restrict__ Kb,
              short* __restrict__ Vtmp)
{
    __shared__ short As[128 * 32];
    __shared__ short Bs[128 * 32];
    const int z = blockIdx.z;
    const short* A  = (z == 0) ? Aq : (z == 1) ? Ak : Av;
    const short* Bt = (z == 0) ? Wqt : (z == 1) ? Wkt : Wvt;
    const float* bias = (z == 0) ? bq : (z == 1) ? bk : bv;
    short* dst = (z == 0) ? Qb : (z == 1) ? Kb : Vtmp;
    const int m0 = blockIdx.y * 128, n0 = blockIdx.x * 128;

    f32x4 acc[4][4];
    gemm_core(A, Bt, m0, n0, As, Bs, acc);

    const int tid = threadIdx.x;
    const int w = tid >> 6, l = tid & 63;
    const int l15 = l & 15, quad = l >> 4;
    const int wm = w >> 1, wn = w & 1;
    const float scale = (z == 0) ? 0.1803368801f : 1.0f;

#pragma unroll
    for (int mi = 0; mi < 4; mi++) {
#pragma unroll
        for (int reg = 0; reg < 4; reg++) {
            int m = m0 + wm * 64 + mi * 16 + quad * 4 + reg;
            int b = m >> 11, t = m & 2047;
#pragma unroll
            for (int ni = 0; ni < 4; ni++) {
                int n = n0 + wn * 64 + ni * 16 + l15;
                float vv = (acc[mi][ni][reg] + bias[n]) * scale;
                int h = n >> 6, dk = n & 63;
                dst[((size_t)(b * HH + h) * TT + t) * DKK + dk] = f2bf(vv);
            }
        }
    }
}

// ---------------------------------------------------------------------------
// Output projection GEMM: out[M][D] = Ab @ Wot^T + bo, fp32 out.
// ---------------------------------------------------------------------------
__global__ __launch_bounds__(256, 3)
void gemm_out(const short* __restrict__ Ab, const short* __restrict__ Wot,
              const float* __restrict__ bo, float* __restrict__ out)
{
    __shared__ short As[128 * 32];
    __shared__ short Bs[128 * 32];
    const int m0 = blockIdx.y * 128, n0 = blockIdx.x * 128;

    f32x4 acc[4][4];
    gemm_core(Ab, Wot, m0, n0, As, Bs, acc);

    const int tid = threadIdx.x;
    const int w = tid >> 6, l = tid & 63;
    const int l15 = l & 15, quad = l >> 4;
    const int wm = w >> 1, wn = w & 1;

#pragma unroll
    for (int mi = 0; mi < 4; mi++) {
#pragma unroll
        for (int reg = 0; reg < 4; reg++) {
            int m = m0 + wm * 64 + mi * 16 + quad * 4 + reg;
#pragma unroll
            for (int ni = 0; ni < 4; ni++) {
                int n = n0 + wn * 64 + ni * 16 + l15;
                out[(size_t)m * DD + n] = acc[mi][ni][reg] + bo[n];
            }
        }
    }
}

// ---------------------------------------------------------------------------
// bf16 MFMA flash attention, BT=128, 8 waves (512 thr), split-S in-block
// (waves 0-3 own s in [0,1024), waves 4-7 own [1024,2048)).
// NO K/V LDS STAGING: K [s][dk] and V^T [dk][s] are read as MFMA fragments
// DIRECTLY from global (16B contiguous per lane). K/V tile working set is
// 16KB -> L1-resident; 4-wave reuse served by L1/L2 (m169 lesson: staging
// L2-fit data is pure overhead). This removes ALL main-loop barriers ->
// waves de-convoy and the MFMA/VALU/LDS phases of different waves overlap.
// Bijective XCD swizzle (512 blocks = 8 XCDs x 64) gives each XCD 4 bh ->
// 2MB K/V working set, L2-fit.
// P never touches LDS (swapped QK^T + pk2 + permlane32/16_swap).
// LDS only holds the final split-S combine buffer (36KB).
// ---------------------------------------------------------------------------
__global__ __launch_bounds__(512, 4)
void attn_mfma(const short* __restrict__ Qb, const short* __restrict__ Kb,
               const short* __restrict__ Vbt, short* __restrict__ Ab)
{
    __shared__ float F[256 * 36];   // 36864 B: split-S combine buffer

    const int tid = threadIdx.x;
    const int w = tid >> 6, l = tid & 63;
    const int wq = w & 3, half = w >> 2;
    const int l15 = l & 15, quad = l >> 4;

    // bijective XCD swizzle: fid -> (tile, bh); XCD k gets bh in [4k,4k+4)
    const int fid = blockIdx.y * 16 + blockIdx.x;
    const int swz = (fid & 7) * 64 + (fid >> 3);
    const int t0 = (swz & 15) * 128;
    const int bh = swz >> 4;
    const size_t hb = (size_t)bh * SSQ * DKK;

    // ---- Q fragments direct from global (B-operand layout, reused 16 tiles)
    short8 qf[2][2];
#pragma unroll
    for (int mf = 0; mf < 2; mf++)
#pragma unroll
        for (int kk = 0; kk < 2; kk++)
            qf[mf][kk] = *(const short8*)(Qb + hb +
                (size_t)(t0 + 32 * wq + 16 * mf + l15) * DKK + kk * 32 + quad * 8);

    // per-lane K/V fragment base pointers for this half's s-range
    const short* kRow = Kb + hb + (size_t)(half * 1024 + l15) * DKK + quad * 8;
    const short* vRow = Vbt + hb + (size_t)l15 * SSQ + half * 1024 + quad * 8;

    f32x4 o[2][4];
#pragma unroll
    for (int mf = 0; mf < 2; mf++)
#pragma unroll
        for (int j = 0; j < 4; j++) o[mf][j] = (f32x4){0.f, 0.f, 0.f, 0.f};
    float lsum[2] = {0.f, 0.f};

    for (int s0 = 0; s0 < 1024; s0 += 64) {
        // ---- S^T = K Q^T : lane holds q-row l15, s = 16np+4quad+reg ----
        f32x4 sc[4][2];
#pragma unroll
        for (int np = 0; np < 4; np++)
#pragma unroll
            for (int mf = 0; mf < 2; mf++) sc[np][mf] = (f32x4){0.f, 0.f, 0.f, 0.f};
        __builtin_amdgcn_s_setprio(1);
#pragma unroll
        for (int kk = 0; kk < 2; kk++) {
#pragma unroll
            for (int np = 0; np < 4; np++) {
                short8 aK = *(const short8*)(kRow + (size_t)(s0 + 16 * np) * DKK + kk * 32);
                sc[np][0] = __builtin_amdgcn_mfma_f32_16x16x32_bf16(aK, qf[0][kk], sc[np][0], 0, 0, 0);
                sc[np][1] = __builtin_amdgcn_mfma_f32_16x16x32_bf16(aK, qf[1][kk], sc[np][1], 0, 0, 0);
            }
        }
        __builtin_amdgcn_s_setprio(0);

        // ---- P = exp2(S); pack + permlane-redistribute into PV A-frags ----
        short8 pa[2][2];
#pragma unroll
        for (int mf = 0; mf < 2; mf++) {
            float pe[4][4];
            float ls = lsum[mf];
#pragma unroll
            for (int np = 0; np < 4; np++) {
#pragma unroll
                for (int reg = 0; reg < 4; reg++) {
                    float p = __builtin_amdgcn_exp2f(sc[np][mf][reg]);
                    pe[np][reg] = p;
                    ls += p;
                }
            }
            lsum[mf] = ls;
#pragma unroll
            for (int kk = 0; kk < 2; kk++) {
                u32x4 wd;
#pragma unroll
                for (int b = 0; b < 2; b++) {
                    unsigned Xw = pk2(pe[2 * kk][2 * b],     pe[2 * kk][2 * b + 1]);
                    unsigned Yw = pk2(pe[2 * kk + 1][2 * b], pe[2 * kk + 1][2 * b + 1]);
                    uint2v s1 = __builtin_amdgcn_permlane32_swap(Xw, Yw, false, false);
                    uint2v s2 = __builtin_amdgcn_permlane16_swap(s1[0], s1[1], false, false);
                    wd[b]     = s2[0];
                    wd[2 + b] = s2[1];
                }
                pa[mf][kk] = __builtin_bit_cast(short8, wd);
            }
        }

        // ---- O += P V ----
        __builtin_amdgcn_s_setprio(1);
#pragma unroll
        for (int kk = 0; kk < 2; kk++) {
#pragma unroll
            for (int np = 0; np < 4; np++) {
                short8 bV = *(const short8*)(vRow + (size_t)(16 * np) * SSQ + s0 + kk * 32);
                o[0][np] = __builtin_amdgcn_mfma_f32_16x16x32_bf16(pa[0][kk], bV, o[0][np], 0, 0, 0);
                o[1][np] = __builtin_amdgcn_mfma_f32_16x16x32_bf16(pa[1][kk], bV, o[1][np], 0, 0, 0);
            }
        }
        __builtin_amdgcn_s_setprio(0);
    }

    // ---- combine the two halves' partials via LDS (lane-aligned) ----
    __syncthreads();
    const int slot = (wq * 64 + l) * 36;
    if (half == 1) {
#pragma unroll
        for (int mf = 0; mf < 2; mf++)
#pragma unroll
            for (int np = 0; np < 4; np++)
                *(f32x4*)&F[slot + (mf * 4 + np) * 4] = o[mf][np];
        F[slot + 32] = lsum[0];
        F[slot + 33] = lsum[1];
    }
    __syncthreads();
    if (half == 0) {
#pragma unroll
        for (int mf = 0; mf < 2; mf++) {
#pragma unroll
            for (int np = 0; np < 4; np++) {
                f32x4 po = *(const f32x4*)&F[slot + (mf * 4 + np) * 4];
                o[mf][np] += po;
            }
            lsum[mf] += F[slot + 32 + mf];
        }

        // ---- epilogue: quad-reduce l per q-row, redistribute, write bf16 ----
        const int b = bh >> 4, h = bh & 15;
#pragma unroll
        for (int mf = 0; mf < 2; mf++) {
            float ls = lsum[mf];
            ls += __shfl_xor(ls, 16);
            ls += __shfl_xor(ls, 32);
            float inv = 1.f / ls;       // lane holds inv for q-row 32wq+16mf+l15
#pragma unroll
            for (int reg = 0; reg < 4; reg++) {
                float invr = __shfl(inv, quad * 4 + reg);
                int t = t0 + 32 * wq + 16 * mf + quad * 4 + reg;
#pragma unroll
                for (int np = 0; np < 4; np++) {
                    Ab[((size_t)(b * TT + t) * HH + h) * DKK + 16 * np + l15] =
                        f2bf(o[mf][np][reg] * invr);
                }
            }
        }
    }
}

// ---------------------------------------------------------------------------
extern "C" void kernel_launch(void* const* d_in, const int* in_sizes, int n_in,
                              void* d_out, int out_size, void* d_ws, size_t ws_size,
                              hipStream_t stream)
{
    const float* query = (const float*)d_in[0];
    const float* value = (const float*)d_in[1];
    const float* key   = (const float*)d_in[2];
    const float* Wq    = (const float*)d_in[3];
    const float* bq    = (const float*)d_in[4];
    const float* Wk    = (const float*)d_in[5];
    const float* bk    = (const float*)d_in[6];
    const float* Wv    = (const float*)d_in[7];
    const float* bv    = (const float*)d_in[8];
    const float* Wo    = (const float*)d_in[9];
    const float* bo    = (const float*)d_in[10];
    float* out = (float*)d_out;

    const size_t actE = (size_t)MM * DD;    // 4.19M elems
    const size_t wE   = (size_t)DD * NN;    // 1.05M elems
    short* p = (short*)d_ws;
    short* Aq   = p; p += actE;
    short* Ak   = p; p += actE;
    short* Av   = p; p += actE;
    short* Wqt  = p; p += wE;
    short* Wkt  = p; p += wE;
    short* Wvt  = p; p += wE;
    short* Wot  = p; p += wE;
    short* Qb   = p; p += actE;
    short* Kb   = p; p += actE;
    short* Vtmp = p; p += actE;
    short* Vbt  = p; p += actE;
    short* Ab   = p; p += actE;

    dim3 blk(256);

    // 1. activations fp32 -> bf16
    to_bf16_acts<<<dim3((unsigned)(actE / 2048), 3), blk, 0, stream>>>(
        query, key, value, Aq, Ak, Av);

    // 2. weights fp32 [K][N] -> bf16 [N][K]
    wtrans<<<dim3(16, 16, 4), blk, 0, stream>>>(Wq, Wk, Wv, Wo, Wqt, Wkt, Wvt, Wot);

    // 3. fused QKV projections; all outputs bf16 [bh][t][dk]
    gemm_qkv<<<dim3(NN / 128, MM / 128, 3), blk, 0, stream>>>(
        Aq, Ak, Av, Wqt, Wkt, Wvt, bq, bk, bv, Qb, Kb, Vtmp);

    // 4. V transpose -> [bh][dk][s]
    vtrans<<<dim3(TT / 64, BB * HH), blk, 0, stream>>>(Vtmp, Vbt);

    // 5. flash attention (split-S, 8 waves, no staging) -> bf16 Ab
    attn_mfma<<<dim3(TT / 128, BB * HH), dim3(512), 0, stream>>>(Qb, Kb, Vbt, Ab);

    // 6. output projection -> fp32 out
    gemm_out<<<dim3(DD / 128, MM / 128), blk, 0, stream>>>(Ab, Wot, bo, out);
}

// Round 4
// 233.781 us; speedup vs baseline: 1.2938x; 1.2938x over previous
//
#include <hip/hip_runtime.h>
#include <math.h>

#define BB  2
#define TT  2048
#define SSQ 2048
#define DD  1024
#define HH  16
#define DKK 64
#define MM  (BB*TT)      // 4096 rows of activations
#define NN  (HH*DKK)     // 1024 proj width

typedef __attribute__((ext_vector_type(8))) short short8;
typedef __attribute__((ext_vector_type(4))) float f32x4;
typedef __attribute__((ext_vector_type(2))) unsigned int uint2v;
typedef __attribute__((ext_vector_type(4))) unsigned int u32x4;

__device__ __forceinline__ short f2bf(float x) {
    unsigned u = __builtin_bit_cast(unsigned, x);
    unsigned r = (u + 0x7FFFu + ((u >> 16) & 1u)) >> 16;
    return (short)r;
}

// pack two f32 into a bf16x2 word by truncation
__device__ __forceinline__ unsigned pk2(float lo, float hi) {
    return (__builtin_bit_cast(unsigned, hi) & 0xFFFF0000u) |
           (__builtin_bit_cast(unsigned, lo) >> 16);
}

__device__ __forceinline__ void glds16(const void* g, void* l) {
    __builtin_amdgcn_global_load_lds(
        (const __attribute__((address_space(1))) void*)g,
        (__attribute__((address_space(3))) void*)l, 16, 0, 0);
}

// ---------------------------------------------------------------------------
// fp32 -> bf16 elementwise (query/key/value), grid (MM*DD/2048, 3)
// ---------------------------------------------------------------------------
__global__ __launch_bounds__(256)
void to_bf16_acts(const float* __restrict__ a0, const float* __restrict__ a1,
                  const float* __restrict__ a2,
                  short* __restrict__ o0, short* __restrict__ o1,
                  short* __restrict__ o2)
{
    int z = blockIdx.y;
    const float* in = (z == 0) ? a0 : (z == 1) ? a1 : a2;
    short* out = (z == 0) ? o0 : (z == 1) ? o1 : o2;
    size_t i0 = ((size_t)blockIdx.x * 256 + threadIdx.x) * 8;
    f32x4 f0 = *(const f32x4*)(in + i0);
    f32x4 f1 = *(const f32x4*)(in + i0 + 4);
    short8 v;
#pragma unroll
    for (int j = 0; j < 4; j++) v[j] = f2bf(f0[j]);
#pragma unroll
    for (int j = 0; j < 4; j++) v[4 + j] = f2bf(f1[j]);
    *(short8*)(out + i0) = v;
}

// ---------------------------------------------------------------------------
// Weight transpose+convert: fp32 [K=1024][N=1024] -> bf16 [N][K].
// grid (16,16,4): z picks which weight.
// ---------------------------------------------------------------------------
__global__ __launch_bounds__(256)
void wtrans(const float* __restrict__ w0, const float* __restrict__ w1,
            const float* __restrict__ w2, const float* __restrict__ w3,
            short* __restrict__ t0, short* __restrict__ t1,
            short* __restrict__ t2, short* __restrict__ t3)
{
    __shared__ float Ls[64][65];
    int z = blockIdx.z;
    const float* in = (z == 0) ? w0 : (z == 1) ? w1 : (z == 2) ? w2 : w3;
    short* out = (z == 0) ? t0 : (z == 1) ? t1 : (z == 2) ? t2 : t3;
    const int r0 = blockIdx.y * 64, c0 = blockIdx.x * 64;
    const int t = threadIdx.x;
    const int r = t >> 2, c4 = t & 3;

    const float* src = in + (size_t)(r0 + r) * DD + c0 + c4 * 16;
#pragma unroll
    for (int i = 0; i < 4; i++) {
        f32x4 f = *(const f32x4*)(src + i * 4);
#pragma unroll
        for (int j = 0; j < 4; j++) Ls[r][c4 * 16 + i * 4 + j] = f[j];
    }
    __syncthreads();

    short8 va, vb;
#pragma unroll
    for (int j = 0; j < 8; j++) va[j] = f2bf(Ls[c4 * 16 + j][r]);
#pragma unroll
    for (int j = 0; j < 8; j++) vb[j] = f2bf(Ls[c4 * 16 + 8 + j][r]);
    short* dst = out + (size_t)(c0 + r) * DD + r0 + c4 * 16;
    *(short8*)dst = va;
    *(short8*)(dst + 8) = vb;
}

// ---------------------------------------------------------------------------
// bf16 transpose: [bh][t][dk=64] -> [bh][dk][t]. grid (TT/64, BB*HH).
// ---------------------------------------------------------------------------
__global__ __launch_bounds__(256)
void vtrans(const short* __restrict__ in, short* __restrict__ out)
{
    __shared__ short Ls[64][72];
    const int bh = blockIdx.y;
    const int t0 = blockIdx.x * 64;
    const int tid = threadIdx.x;
    const int r = tid >> 2, c4 = tid & 3;

    const short* src = in + ((size_t)bh * TT + t0 + r) * DKK + c4 * 16;
    *(short8*)&Ls[r][c4 * 16]     = *(const short8*)(src);
    *(short8*)&Ls[r][c4 * 16 + 8] = *(const short8*)(src + 8);
    __syncthreads();

    short8 a, b;
#pragma unroll
    for (int j = 0; j < 8; j++) a[j] = Ls[c4 * 16 + j][r];
#pragma unroll
    for (int j = 0; j < 8; j++) b[j] = Ls[c4 * 16 + 8 + j][r];
    short* dst = out + ((size_t)bh * DKK + r) * SSQ + t0 + c4 * 16;
    *(short8*)dst = a;
    *(short8*)(dst + 8) = b;
}

// ---------------------------------------------------------------------------
// m97-style bf16 GEMM core: C128x128 = A[M][K] @ Bt[N][K]^T, BK=32,
// 256 thr = 4 waves (2x2), each wave 64x64 = 4x4 MFMA tiles.
// ---------------------------------------------------------------------------
__device__ __forceinline__ void gemm_core(const short* __restrict__ A,
                                          const short* __restrict__ Bt,
                                          int m0, int n0,
                                          short* As, short* Bs,
                                          f32x4 (&acc)[4][4])
{
    const int tid = threadIdx.x;
    const int w = tid >> 6, l = tid & 63;
    const int l15 = l & 15, quad = l >> 4;
    const int wm = w >> 1, wn = w & 1;

#pragma unroll
    for (int i = 0; i < 4; i++)
#pragma unroll
        for (int j = 0; j < 4; j++) acc[i][j] = (f32x4){0.f, 0.f, 0.f, 0.f};

    const int r = tid >> 2, cseg = tid & 3;
    const short* gA = A + (size_t)(m0 + r) * DD + cseg * 8;
    const short* gB = Bt + (size_t)(n0 + r) * DD + cseg * 8;
    short* ldsA = As + w * 512;
    short* ldsB = Bs + w * 512;

    for (int k0 = 0; k0 < DD; k0 += 32) {
        glds16(gA + k0,                 ldsA);
        glds16(gA + (size_t)64 * DD + k0, ldsA + 2048);
        glds16(gB + k0,                 ldsB);
        glds16(gB + (size_t)64 * DD + k0, ldsB + 2048);
        __syncthreads();

        short8 bF[4];
#pragma unroll
        for (int ni = 0; ni < 4; ni++)
            bF[ni] = *(const short8*)&Bs[(wn * 64 + ni * 16 + l15) * 32 + quad * 8];
#pragma unroll
        for (int mi = 0; mi < 4; mi++) {
            short8 aF = *(const short8*)&As[(wm * 64 + mi * 16 + l15) * 32 + quad * 8];
#pragma unroll
            for (int ni = 0; ni < 4; ni++)
                acc[mi][ni] = __builtin_amdgcn_mfma_f32_16x16x32_bf16(aF, bF[ni], acc[mi][ni], 0, 0, 0);
        }
        __syncthreads();
    }
}

// ---------------------------------------------------------------------------
// QKV projection GEMM. z picks {Q,K,V}. All outputs bf16 [bh][t][dk]
// (coalesced 32B-segment stores); V transposed later by vtrans.
// Q scaled by 1/sqrt(dk)*log2(e) so attention uses exp2.
// ---------------------------------------------------------------------------
__global__ __launch_bounds__(256, 3)
void gemm_qkv(const short* __restrict__ Aq, const short* __restrict__ Ak,
              const short* __restrict__ Av,
              const short* __restrict__ Wqt, const short* __restrict__ Wkt,
              const short* __restrict__ Wvt,
              const float* __restrict__ bq, const float* __restrict__ bk,
              const float* __restrict__ bv,
              short* __restrict__ Qb, short* __restrict__ Kb,
              short* __restrict__ Vtmp)
{
    __shared__ short As[128 * 32];
    __shared__ short Bs[128 * 32];
    const int z = blockIdx.z;
    const short* A  = (z == 0) ? Aq : (z == 1) ? Ak : Av;
    const short* Bt = (z == 0) ? Wqt : (z == 1) ? Wkt : Wvt;
    const float* bias = (z == 0) ? bq : (z == 1) ? bk : bv;
    short* dst = (z == 0) ? Qb : (z == 1) ? Kb : Vtmp;
    const int m0 = blockIdx.y * 128, n0 = blockIdx.x * 128;

    f32x4 acc[4][4];
    gemm_core(A, Bt, m0, n0, As, Bs, acc);

    const int tid = threadIdx.x;
    const int w = tid >> 6, l = tid & 63;
    const int l15 = l & 15, quad = l >> 4;
    const int wm = w >> 1, wn = w & 1;
    const float scale = (z == 0) ? 0.1803368801f : 1.0f;

#pragma unroll
    for (int mi = 0; mi < 4; mi++) {
#pragma unroll
        for (int reg = 0; reg < 4; reg++) {
            int m = m0 + wm * 64 + mi * 16 + quad * 4 + reg;
            int b = m >> 11, t = m & 2047;
#pragma unroll
            for (int ni = 0; ni < 4; ni++) {
                int n = n0 + wn * 64 + ni * 16 + l15;
                float vv = (acc[mi][ni][reg] + bias[n]) * scale;
                int h = n >> 6, dk = n & 63;
                dst[((size_t)(b * HH + h) * TT + t) * DKK + dk] = f2bf(vv);
            }
        }
    }
}

// ---------------------------------------------------------------------------
// Output projection GEMM: out[M][D] = Ab @ Wot^T + bo, fp32 out.
// ---------------------------------------------------------------------------
__global__ __launch_bounds__(256, 3)
void gemm_out(const short* __restrict__ Ab, const short* __restrict__ Wot,
              const float* __restrict__ bo, float* __restrict__ out)
{
    __shared__ short As[128 * 32];
    __shared__ short Bs[128 * 32];
    const int m0 = blockIdx.y * 128, n0 = blockIdx.x * 128;

    f32x4 acc[4][4];
    gemm_core(Ab, Wot, m0, n0, As, Bs, acc);

    const int tid = threadIdx.x;
    const int w = tid >> 6, l = tid & 63;
    const int l15 = l & 15, quad = l >> 4;
    const int wm = w >> 1, wn = w & 1;

#pragma unroll
    for (int mi = 0; mi < 4; mi++) {
#pragma unroll
        for (int reg = 0; reg < 4; reg++) {
            int m = m0 + wm * 64 + mi * 16 + quad * 4 + reg;
#pragma unroll
            for (int ni = 0; ni < 4; ni++) {
                int n = n0 + wn * 64 + ni * 16 + l15;
                out[(size_t)m * DD + n] = acc[mi][ni][reg] + bo[n];
            }
        }
    }
}

// ---------------------------------------------------------------------------
// bf16 MFMA flash attention, BT=128, 4 waves (256 thr), wave w owns q-rows
// 32w..32w+31 (2 m-frags). Round-1 staged skeleton (K/V double-buffered in
// LDS, register prefetch, ONE barrier per 64-s tile) -- round 3 proved that
// direct-global fragments are L2-latency-bound (MfmaUtil 11%), so staging
// stays. Proven additions:
//  * P never touches LDS: swapped QK^T (mfma(K,Q) -> lane holds q-row l15
//    at s=16np+4quad+reg), inline exp2 -> pk2 -> permlane32/16_swap gives
//    the PV A-frag in registers. Kills 12 LDS ops + fence per tile.
//  * Q frags direct from global (one-time); QPs buffer deleted -> LDS
//    36864 B -> 3 blocks/CU at __launch_bounds__(256,3) (no 128-cap spill).
//  * Bijective XCD swizzle: XCD k gets bh in [4k,4k+4) -> 2MB K/V per XCD,
//    L2-fit (round 3: FETCH 70 -> 12 MB).
//  * setprio(1) around MFMA clusters.
// ---------------------------------------------------------------------------
__global__ __launch_bounds__(256, 3)
void attn_mfma(const short* __restrict__ Qb, const short* __restrict__ Kb,
               const short* __restrict__ Vbt, short* __restrict__ Ab)
{
    // [dbuf][{K|V}] each 64x72 shorts: K at dbo, V at dbo+4608
    __shared__ short KV[2 * 2 * 64 * 72];   // 36864 B

    const int tid = threadIdx.x;
    const int w = tid >> 6, l = tid & 63;
    const int l15 = l & 15, quad = l >> 4;

    // bijective XCD swizzle: fid -> (tile, bh); XCD k gets bh in [4k,4k+4)
    const int fid = blockIdx.y * 16 + blockIdx.x;
    const int swz = (fid & 7) * 64 + (fid >> 3);
    const int t0 = (swz & 15) * 128;
    const int bh = swz >> 4;
    const size_t hb = (size_t)bh * SSQ * DKK;
    const int r = tid >> 2, c4 = tid & 3;

    // ---- Q fragments direct from global (B-operand layout, reused 32 tiles)
    short8 qf[2][2];
#pragma unroll
    for (int mf = 0; mf < 2; mf++)
#pragma unroll
        for (int kk = 0; kk < 2; kk++)
            qf[mf][kk] = *(const short8*)(Qb + hb +
                (size_t)(t0 + 32 * w + 16 * mf + l15) * DKK + kk * 32 + quad * 8);

    // ---- prefetch K/V tile 0 into registers ----
    const short* gkb = Kb + hb + (size_t)r * DKK + c4 * 16;
    const short* gvb = Vbt + hb + (size_t)r * SSQ + c4 * 16;
    short8 kr0 = *(const short8*)(gkb + 0);
    short8 kr1 = *(const short8*)(gkb + 8);
    short8 vr0 = *(const short8*)(gvb + 0);
    short8 vr1 = *(const short8*)(gvb + 8);

    f32x4 o[2][4];
#pragma unroll
    for (int mf = 0; mf < 2; mf++)
#pragma unroll
        for (int j = 0; j < 4; j++) o[mf][j] = (f32x4){0.f, 0.f, 0.f, 0.f};
    float lsum[2] = {0.f, 0.f};

    short* skb = KV + r * 72 + c4 * 16;   // staging write base

    for (int s0 = 0; s0 < SSQ; s0 += 64) {
        const int dbo = (s0 & 64) ? 9216 : 0;
        // write current K/V regs into buffer `dbo`
        *(short8*)(skb + dbo)          = kr0;
        *(short8*)(skb + dbo + 8)      = kr1;
        *(short8*)(skb + dbo + 4608)   = vr0;
        *(short8*)(skb + dbo + 4616)   = vr1;
        // issue next-tile global loads (covered by this tile's compute)
        if (s0 + 64 < SSQ) {
            const short* gk = gkb + (size_t)(s0 + 64) * DKK;
            const short* gv = gvb + (s0 + 64);
            kr0 = *(const short8*)(gk + 0);
            kr1 = *(const short8*)(gk + 8);
            vr0 = *(const short8*)(gv + 0);
            vr1 = *(const short8*)(gv + 8);
        }
        __syncthreads();          // tile `dbo` visible; prev-buffer readers done
        const short* kb_ = KV + dbo;
        const short* vb_ = kb_ + 4608;

        // ---- S^T = K Q^T : lane holds q-row l15, s = 16np+4quad+reg ----
        f32x4 sc[4][2];
#pragma unroll
        for (int np = 0; np < 4; np++)
#pragma unroll
            for (int mf = 0; mf < 2; mf++) sc[np][mf] = (f32x4){0.f, 0.f, 0.f, 0.f};
        __builtin_amdgcn_s_setprio(1);
#pragma unroll
        for (int kk = 0; kk < 2; kk++) {
#pragma unroll
            for (int np = 0; np < 4; np++) {
                short8 aK = *(const short8*)&kb_[(16 * np + l15) * 72 + kk * 32 + quad * 8];
                sc[np][0] = __builtin_amdgcn_mfma_f32_16x16x32_bf16(aK, qf[0][kk], sc[np][0], 0, 0, 0);
                sc[np][1] = __builtin_amdgcn_mfma_f32_16x16x32_bf16(aK, qf[1][kk], sc[np][1], 0, 0, 0);
            }
        }
        __builtin_amdgcn_s_setprio(0);

        // ---- P = exp2(S); inline pack + permlane into PV A-frags ----
        short8 pa[2][2];
#pragma unroll
        for (int mf = 0; mf < 2; mf++) {
            float ls = lsum[mf];
#pragma unroll
            for (int kk = 0; kk < 2; kk++) {
                u32x4 wd;
#pragma unroll
                for (int b = 0; b < 2; b++) {
                    float p00 = __builtin_amdgcn_exp2f(sc[2 * kk][mf][2 * b]);
                    float p01 = __builtin_amdgcn_exp2f(sc[2 * kk][mf][2 * b + 1]);
                    float p10 = __builtin_amdgcn_exp2f(sc[2 * kk + 1][mf][2 * b]);
                    float p11 = __builtin_amdgcn_exp2f(sc[2 * kk + 1][mf][2 * b + 1]);
                    ls += (p00 + p01) + (p10 + p11);
                    unsigned Xw = pk2(p00, p01);
                    unsigned Yw = pk2(p10, p11);
                    uint2v s1 = __builtin_amdgcn_permlane32_swap(Xw, Yw, false, false);
                    uint2v s2 = __builtin_amdgcn_permlane16_swap(s1[0], s1[1], false, false);
                    wd[b]     = s2[0];
                    wd[2 + b] = s2[1];
                }
                pa[mf][kk] = __builtin_bit_cast(short8, wd);
            }
            lsum[mf] = ls;
        }

        // ---- O += P V ----
        __builtin_amdgcn_s_setprio(1);
#pragma unroll
        for (int kk = 0; kk < 2; kk++) {
#pragma unroll
            for (int np = 0; np < 4; np++) {
                short8 bV = *(const short8*)&vb_[(16 * np + l15) * 72 + kk * 32 + quad * 8];
                o[0][np] = __builtin_amdgcn_mfma_f32_16x16x32_bf16(pa[0][kk], bV, o[0][np], 0, 0, 0);
                o[1][np] = __builtin_amdgcn_mfma_f32_16x16x32_bf16(pa[1][kk], bV, o[1][np], 0, 0, 0);
            }
        }
        __builtin_amdgcn_s_setprio(0);
    }

    // ---- epilogue: reduce l per q-row, redistribute, write bf16 Ab ----
    const int b = bh >> 4, h = bh & 15;
#pragma unroll
    for (int mf = 0; mf < 2; mf++) {
        float ls = lsum[mf];
        ls += __shfl_xor(ls, 16);
        ls += __shfl_xor(ls, 32);
        float inv = 1.f / ls;       // lane holds inv for q-row 32w+16mf+l15
#pragma unroll
        for (int reg = 0; reg < 4; reg++) {
            float invr = __shfl(inv, quad * 4 + reg);
            int t = t0 + 32 * w + 16 * mf + quad * 4 + reg;
#pragma unroll
            for (int np = 0; np < 4; np++) {
                Ab[((size_t)(b * TT + t) * HH + h) * DKK + 16 * np + l15] =
                    f2bf(o[mf][np][reg] * invr);
            }
        }
    }
}

// ---------------------------------------------------------------------------
extern "C" void kernel_launch(void* const* d_in, const int* in_sizes, int n_in,
                              void* d_out, int out_size, void* d_ws, size_t ws_size,
                              hipStream_t stream)
{
    const float* query = (const float*)d_in[0];
    const float* value = (const float*)d_in[1];
    const float* key   = (const float*)d_in[2];
    const float* Wq    = (const float*)d_in[3];
    const float* bq    = (const float*)d_in[4];
    const float* Wk    = (const float*)d_in[5];
    const float* bk    = (const float*)d_in[6];
    const float* Wv    = (const float*)d_in[7];
    const float* bv    = (const float*)d_in[8];
    const float* Wo    = (const float*)d_in[9];
    const float* bo    = (const float*)d_in[10];
    float* out = (float*)d_out;

    const size_t actE = (size_t)MM * DD;    // 4.19M elems
    const size_t wE   = (size_t)DD * NN;    // 1.05M elems
    short* p = (short*)d_ws;
    short* Aq   = p; p += actE;
    short* Ak   = p; p += actE;
    short* Av   = p; p += actE;
    short* Wqt  = p; p += wE;
    short* Wkt  = p; p += wE;
    short* Wvt  = p; p += wE;
    short* Wot  = p; p += wE;
    short* Qb   = p; p += actE;
    short* Kb   = p; p += actE;
    short* Vtmp = p; p += actE;
    short* Vbt  = p; p += actE;
    short* Ab   = p; p += actE;

    dim3 blk(256);

    // 1. activations fp32 -> bf16
    to_bf16_acts<<<dim3((unsigned)(actE / 2048), 3), blk, 0, stream>>>(
        query, key, value, Aq, Ak, Av);

    // 2. weights fp32 [K][N] -> bf16 [N][K]
    wtrans<<<dim3(16, 16, 4), blk, 0, stream>>>(Wq, Wk, Wv, Wo, Wqt, Wkt, Wvt, Wot);

    // 3. fused QKV projections; all outputs bf16 [bh][t][dk]
    gemm_qkv<<<dim3(NN / 128, MM / 128, 3), blk, 0, stream>>>(
        Aq, Ak, Av, Wqt, Wkt, Wvt, bq, bk, bv, Qb, Kb, Vtmp);

    // 4. V transpose -> [bh][dk][s]
    vtrans<<<dim3(TT / 64, BB * HH), blk, 0, stream>>>(Vtmp, Vbt);

    // 5. flash attention (staged, permlane P, XCD swizzle) -> bf16 Ab
    attn_mfma<<<dim3(TT / 128, BB * HH), blk, 0, stream>>>(Qb, Kb, Vbt, Ab);

    // 6. output projection -> fp32 out
    gemm_out<<<dim3(DD / 128, MM / 128), blk, 0, stream>>>(Ab, Wot, bo, out);
}

// Round 5
// 227.993 us; speedup vs baseline: 1.3267x; 1.0254x over previous
//
#include <hip/hip_runtime.h>
#include <math.h>

#define BB  2
#define TT  2048
#define SSQ 2048
#define DD  1024
#define HH  16
#define DKK 64
#define MM  (BB*TT)      // 4096 rows of activations
#define NN  (HH*DKK)     // 1024 proj width

typedef __attribute__((ext_vector_type(8))) short short8;
typedef __attribute__((ext_vector_type(4))) float f32x4;
typedef __attribute__((ext_vector_type(2))) unsigned int uint2v;
typedef __attribute__((ext_vector_type(4))) unsigned int u32x4;

__device__ __forceinline__ short f2bf(float x) {
    unsigned u = __builtin_bit_cast(unsigned, x);
    unsigned r = (u + 0x7FFFu + ((u >> 16) & 1u)) >> 16;
    return (short)r;
}

// pack two f32 into a bf16x2 word by truncation
__device__ __forceinline__ unsigned pk2(float lo, float hi) {
    return (__builtin_bit_cast(unsigned, hi) & 0xFFFF0000u) |
           (__builtin_bit_cast(unsigned, lo) >> 16);
}

__device__ __forceinline__ void glds16(const void* g, void* l) {
    __builtin_amdgcn_global_load_lds(
        (const __attribute__((address_space(1))) void*)g,
        (__attribute__((address_space(3))) void*)l, 16, 0, 0);
}

// ---------------------------------------------------------------------------
// fp32 -> bf16 elementwise (query/key/value), grid (MM*DD/2048, 3)
// ---------------------------------------------------------------------------
__global__ __launch_bounds__(256)
void to_bf16_acts(const float* __restrict__ a0, const float* __restrict__ a1,
                  const float* __restrict__ a2,
                  short* __restrict__ o0, short* __restrict__ o1,
                  short* __restrict__ o2)
{
    int z = blockIdx.y;
    const float* in = (z == 0) ? a0 : (z == 1) ? a1 : a2;
    short* out = (z == 0) ? o0 : (z == 1) ? o1 : o2;
    size_t i0 = ((size_t)blockIdx.x * 256 + threadIdx.x) * 8;
    f32x4 f0 = *(const f32x4*)(in + i0);
    f32x4 f1 = *(const f32x4*)(in + i0 + 4);
    short8 v;
#pragma unroll
    for (int j = 0; j < 4; j++) v[j] = f2bf(f0[j]);
#pragma unroll
    for (int j = 0; j < 4; j++) v[4 + j] = f2bf(f1[j]);
    *(short8*)(out + i0) = v;
}

// ---------------------------------------------------------------------------
// Weight transpose+convert: fp32 [K=1024][N=1024] -> bf16 [N][K].
// grid (16,16,4): z picks which weight.
// ---------------------------------------------------------------------------
__global__ __launch_bounds__(256)
void wtrans(const float* __restrict__ w0, const float* __restrict__ w1,
            const float* __restrict__ w2, const float* __restrict__ w3,
            short* __restrict__ t0, short* __restrict__ t1,
            short* __restrict__ t2, short* __restrict__ t3)
{
    __shared__ float Ls[64][65];
    int z = blockIdx.z;
    const float* in = (z == 0) ? w0 : (z == 1) ? w1 : (z == 2) ? w2 : w3;
    short* out = (z == 0) ? t0 : (z == 1) ? t1 : (z == 2) ? t2 : t3;
    const int r0 = blockIdx.y * 64, c0 = blockIdx.x * 64;
    const int t = threadIdx.x;
    const int r = t >> 2, c4 = t & 3;

    const float* src = in + (size_t)(r0 + r) * DD + c0 + c4 * 16;
#pragma unroll
    for (int i = 0; i < 4; i++) {
        f32x4 f = *(const f32x4*)(src + i * 4);
#pragma unroll
        for (int j = 0; j < 4; j++) Ls[r][c4 * 16 + i * 4 + j] = f[j];
    }
    __syncthreads();

    short8 va, vb;
#pragma unroll
    for (int j = 0; j < 8; j++) va[j] = f2bf(Ls[c4 * 16 + j][r]);
#pragma unroll
    for (int j = 0; j < 8; j++) vb[j] = f2bf(Ls[c4 * 16 + 8 + j][r]);
    short* dst = out + (size_t)(c0 + r) * DD + r0 + c4 * 16;
    *(short8*)dst = va;
    *(short8*)(dst + 8) = vb;
}

// ---------------------------------------------------------------------------
// bf16 transpose: [bh][t][dk=64] -> [bh][dk][t]. grid (TT/64, BB*HH).
// ---------------------------------------------------------------------------
__global__ __launch_bounds__(256)
void vtrans(const short* __restrict__ in, short* __restrict__ out)
{
    __shared__ short Ls[64][72];
    const int bh = blockIdx.y;
    const int t0 = blockIdx.x * 64;
    const int tid = threadIdx.x;
    const int r = tid >> 2, c4 = tid & 3;

    const short* src = in + ((size_t)bh * TT + t0 + r) * DKK + c4 * 16;
    *(short8*)&Ls[r][c4 * 16]     = *(const short8*)(src);
    *(short8*)&Ls[r][c4 * 16 + 8] = *(const short8*)(src + 8);
    __syncthreads();

    short8 a, b;
#pragma unroll
    for (int j = 0; j < 8; j++) a[j] = Ls[c4 * 16 + j][r];
#pragma unroll
    for (int j = 0; j < 8; j++) b[j] = Ls[c4 * 16 + 8 + j][r];
    short* dst = out + ((size_t)bh * DKK + r) * SSQ + t0 + c4 * 16;
    *(short8*)dst = a;
    *(short8*)(dst + 8) = b;
}

// ---------------------------------------------------------------------------
// m97-style bf16 GEMM core: C128x128 = A[M][K] @ Bt[N][K]^T, BK=32,
// 256 thr = 4 waves (2x2), each wave 64x64 = 4x4 MFMA tiles.
// ---------------------------------------------------------------------------
__device__ __forceinline__ void gemm_core(const short* __restrict__ A,
                                          const short* __restrict__ Bt,
                                          int m0, int n0,
                                          short* As, short* Bs,
                                          f32x4 (&acc)[4][4])
{
    const int tid = threadIdx.x;
    const int w = tid >> 6, l = tid & 63;
    const int l15 = l & 15, quad = l >> 4;
    const int wm = w >> 1, wn = w & 1;

#pragma unroll
    for (int i = 0; i < 4; i++)
#pragma unroll
        for (int j = 0; j < 4; j++) acc[i][j] = (f32x4){0.f, 0.f, 0.f, 0.f};

    const int r = tid >> 2, cseg = tid & 3;
    const short* gA = A + (size_t)(m0 + r) * DD + cseg * 8;
    const short* gB = Bt + (size_t)(n0 + r) * DD + cseg * 8;
    short* ldsA = As + w * 512;
    short* ldsB = Bs + w * 512;

    for (int k0 = 0; k0 < DD; k0 += 32) {
        glds16(gA + k0,                 ldsA);
        glds16(gA + (size_t)64 * DD + k0, ldsA + 2048);
        glds16(gB + k0,                 ldsB);
        glds16(gB + (size_t)64 * DD + k0, ldsB + 2048);
        __syncthreads();

        short8 bF[4];
#pragma unroll
        for (int ni = 0; ni < 4; ni++)
            bF[ni] = *(const short8*)&Bs[(wn * 64 + ni * 16 + l15) * 32 + quad * 8];
#pragma unroll
        for (int mi = 0; mi < 4; mi++) {
            short8 aF = *(const short8*)&As[(wm * 64 + mi * 16 + l15) * 32 + quad * 8];
#pragma unroll
            for (int ni = 0; ni < 4; ni++)
                acc[mi][ni] = __builtin_amdgcn_mfma_f32_16x16x32_bf16(aF, bF[ni], acc[mi][ni], 0, 0, 0);
        }
        __syncthreads();
    }
}

// ---------------------------------------------------------------------------
// QKV projection GEMM. z picks {Q,K,V}. All outputs bf16 [bh][t][dk]
// (coalesced 32B-segment stores); V transposed later by vtrans.
// Q scaled by 1/sqrt(dk)*log2(e) so attention uses exp2.
// ---------------------------------------------------------------------------
__global__ __launch_bounds__(256, 3)
void gemm_qkv(const short* __restrict__ Aq, const short* __restrict__ Ak,
              const short* __restrict__ Av,
              const short* __restrict__ Wqt, const short* __restrict__ Wkt,
              const short* __restrict__ Wvt,
              const float* __restrict__ bq, const float* __restrict__ bk,
              const float* __restrict__ bv,
              short* __restrict__ Qb, short* __restrict__ Kb,
              short* __restrict__ Vtmp)
{
    __shared__ short As[128 * 32];
    __shared__ short Bs[128 * 32];
    const int z = blockIdx.z;
    const short* A  = (z == 0) ? Aq : (z == 1) ? Ak : Av;
    const short* Bt = (z == 0) ? Wqt : (z == 1) ? Wkt : Wvt;
    const float* bias = (z == 0) ? bq : (z == 1) ? bk : bv;
    short* dst = (z == 0) ? Qb : (z == 1) ? Kb : Vtmp;
    const int m0 = blockIdx.y * 128, n0 = blockIdx.x * 128;

    f32x4 acc[4][4];
    gemm_core(A, Bt, m0, n0, As, Bs, acc);

    const int tid = threadIdx.x;
    const int w = tid >> 6, l = tid & 63;
    const int l15 = l & 15, quad = l >> 4;
    const int wm = w >> 1, wn = w & 1;
    const float scale = (z == 0) ? 0.1803368801f : 1.0f;

#pragma unroll
    for (int mi = 0; mi < 4; mi++) {
#pragma unroll
        for (int reg = 0; reg < 4; reg++) {
            int m = m0 + wm * 64 + mi * 16 + quad * 4 + reg;
            int b = m >> 11, t = m & 2047;
#pragma unroll
            for (int ni = 0; ni < 4; ni++) {
                int n = n0 + wn * 64 + ni * 16 + l15;
                float vv = (acc[mi][ni][reg] + bias[n]) * scale;
                int h = n >> 6, dk = n & 63;
                dst[((size_t)(b * HH + h) * TT + t) * DKK + dk] = f2bf(vv);
            }
        }
    }
}

// ---------------------------------------------------------------------------
// Output projection GEMM: out[M][D] = Ab @ Wot^T + bo, fp32 out.
// 64x128 tiles -> grid (8,64) = 512 blocks = 2 blocks/CU (was 256 = 1/CU,
// fully latency-exposed). W is 2MB -> L2-resident, extra B re-reads free.
// 4 waves 2x2: wave tile 32x64 (mi<2, ni<4).
// ---------------------------------------------------------------------------
__global__ __launch_bounds__(256, 3)
void gemm_out(const short* __restrict__ Ab, const short* __restrict__ Wot,
              const float* __restrict__ bo, float* __restrict__ out)
{
    __shared__ short As[64 * 32];
    __shared__ short Bs[128 * 32];
    const int m0 = blockIdx.y * 64, n0 = blockIdx.x * 128;
    const int tid = threadIdx.x;
    const int w = tid >> 6, l = tid & 63;
    const int l15 = l & 15, quad = l >> 4;
    const int wm = w >> 1, wn = w & 1;

    f32x4 acc[2][4];
#pragma unroll
    for (int i = 0; i < 2; i++)
#pragma unroll
        for (int j = 0; j < 4; j++) acc[i][j] = (f32x4){0.f, 0.f, 0.f, 0.f};

    const int r = tid >> 2, cseg = tid & 3;
    const short* gA = Ab + (size_t)(m0 + r) * DD + cseg * 8;
    const short* gB = Wot + (size_t)(n0 + r) * DD + cseg * 8;
    short* ldsA = As + w * 512;
    short* ldsB = Bs + w * 512;

    for (int k0 = 0; k0 < DD; k0 += 32) {
        glds16(gA + k0,                   ldsA);
        glds16(gB + k0,                   ldsB);
        glds16(gB + (size_t)64 * DD + k0, ldsB + 2048);
        __syncthreads();

        short8 bF[4];
#pragma unroll
        for (int ni = 0; ni < 4; ni++)
            bF[ni] = *(const short8*)&Bs[(wn * 64 + ni * 16 + l15) * 32 + quad * 8];
#pragma unroll
        for (int mi = 0; mi < 2; mi++) {
            short8 aF = *(const short8*)&As[(wm * 32 + mi * 16 + l15) * 32 + quad * 8];
#pragma unroll
            for (int ni = 0; ni < 4; ni++)
                acc[mi][ni] = __builtin_amdgcn_mfma_f32_16x16x32_bf16(aF, bF[ni], acc[mi][ni], 0, 0, 0);
        }
        __syncthreads();
    }

#pragma unroll
    for (int mi = 0; mi < 2; mi++) {
#pragma unroll
        for (int reg = 0; reg < 4; reg++) {
            int m = m0 + wm * 32 + mi * 16 + quad * 4 + reg;
#pragma unroll
            for (int ni = 0; ni < 4; ni++) {
                int n = n0 + wn * 64 + ni * 16 + l15;
                out[(size_t)m * DD + n] = acc[mi][ni][reg] + bo[n];
            }
        }
    }
}

// ---------------------------------------------------------------------------
// bf16 MFMA flash attention, split-S ACROSS BLOCKS: grid (16, 32, 2), z=half
// owns s in [1024*half, 1024*half+1024). 1024 blocks -> 4 blocks/CU (LDS
// 4x36.9KB = 147KB, VGPR<=64) = 4 waves/SIMD, double the latency cover of
// round 4's grid-capped 2 blocks/CU. Writes UNNORMALIZED partial O (f32)
// and row-sums l to workspace; combine_norm merges halves.
// Row-sum l computed FOR FREE via mfma(P, ones): lacc[mf][reg] lands in the
// same (quad,reg) layout as o -> no epilogue shuffles, -32 VALU adds/tile.
// Keeps: K/V double-buffered LDS staging (r3: direct-global is latency-
// bound), ONE barrier/tile, permlane P-path (P never touches LDS), Q frags
// direct from global, XCD swizzle (bh-contiguous per XCD; z adds +512 to
// linear block id = same XCD), setprio around MFMA clusters.
// ---------------------------------------------------------------------------
__global__ __launch_bounds__(256, 4)
void attn_mfma(const short* __restrict__ Qb, const short* __restrict__ Kb,
               const short* __restrict__ Vbt,
               float* __restrict__ O1, float* __restrict__ O2,
               float* __restrict__ l1, float* __restrict__ l2)
{
    // [dbuf][{K|V}] each 64x72 shorts: K at dbo, V at dbo+4608
    __shared__ short KV[2 * 2 * 64 * 72];   // 36864 B

    const int tid = threadIdx.x;
    const int w = tid >> 6, l = tid & 63;
    const int l15 = l & 15, quad = l >> 4;

    // bijective XCD swizzle: fid -> (tile, bh); XCD k gets bh in [4k,4k+4)
    const int fid = blockIdx.y * 16 + blockIdx.x;
    const int swz = (fid & 7) * 64 + (fid >> 3);
    const int t0 = (swz & 15) * 128;
    const int bh = swz >> 4;
    const int half = blockIdx.z;
    const size_t hb = (size_t)bh * SSQ * DKK;
    const int r = tid >> 2, c4 = tid & 3;
    const int sbase = half * 1024;

    // ---- Q fragments direct from global (B-operand layout, reused 16 tiles)
    short8 qf[2][2];
#pragma unroll
    for (int mf = 0; mf < 2; mf++)
#pragma unroll
        for (int kk = 0; kk < 2; kk++)
            qf[mf][kk] = *(const short8*)(Qb + hb +
                (size_t)(t0 + 32 * w + 16 * mf + l15) * DKK + kk * 32 + quad * 8);

    // ---- prefetch K/V tile 0 of this half's s-range ----
    const short* gkb = Kb + hb + (size_t)(sbase + r) * DKK + c4 * 16;
    const short* gvb = Vbt + hb + (size_t)r * SSQ + sbase + c4 * 16;
    short8 kr0 = *(const short8*)(gkb + 0);
    short8 kr1 = *(const short8*)(gkb + 8);
    short8 vr0 = *(const short8*)(gvb + 0);
    short8 vr1 = *(const short8*)(gvb + 8);

    f32x4 o[2][4];
#pragma unroll
    for (int mf = 0; mf < 2; mf++)
#pragma unroll
        for (int j = 0; j < 4; j++) o[mf][j] = (f32x4){0.f, 0.f, 0.f, 0.f};
    f32x4 lacc[2] = {(f32x4){0.f, 0.f, 0.f, 0.f}, (f32x4){0.f, 0.f, 0.f, 0.f}};
    const short8 ones = {(short)0x3F80, (short)0x3F80, (short)0x3F80, (short)0x3F80,
                         (short)0x3F80, (short)0x3F80, (short)0x3F80, (short)0x3F80};

    short* skb = KV + r * 72 + c4 * 16;   // staging write base

    for (int s0 = 0; s0 < 1024; s0 += 64) {
        const int dbo = (s0 & 64) ? 9216 : 0;
        // write current K/V regs into buffer `dbo`
        *(short8*)(skb + dbo)          = kr0;
        *(short8*)(skb + dbo + 8)      = kr1;
        *(short8*)(skb + dbo + 4608)   = vr0;
        *(short8*)(skb + dbo + 4616)   = vr1;
        // issue next-tile global loads (covered by this tile's compute)
        if (s0 + 64 < 1024) {
            const short* gk = gkb + (size_t)(s0 + 64) * DKK;
            const short* gv = gvb + (s0 + 64);
            kr0 = *(const short8*)(gk + 0);
            kr1 = *(const short8*)(gk + 8);
            vr0 = *(const short8*)(gv + 0);
            vr1 = *(const short8*)(gv + 8);
        }
        __syncthreads();          // tile `dbo` visible; prev-buffer readers done
        const short* kb_ = KV + dbo;
        const short* vb_ = kb_ + 4608;

        // ---- S^T = K Q^T : lane holds q-row l15, s = 16np+4quad+reg ----
        f32x4 sc[4][2];
#pragma unroll
        for (int np = 0; np < 4; np++)
#pragma unroll
            for (int mf = 0; mf < 2; mf++) sc[np][mf] = (f32x4){0.f, 0.f, 0.f, 0.f};
        __builtin_amdgcn_s_setprio(1);
#pragma unroll
        for (int kk = 0; kk < 2; kk++) {
#pragma unroll
            for (int np = 0; np < 4; np++) {
                short8 aK = *(const short8*)&kb_[(16 * np + l15) * 72 + kk * 32 + quad * 8];
                sc[np][0] = __builtin_amdgcn_mfma_f32_16x16x32_bf16(aK, qf[0][kk], sc[np][0], 0, 0, 0);
                sc[np][1] = __builtin_amdgcn_mfma_f32_16x16x32_bf16(aK, qf[1][kk], sc[np][1], 0, 0, 0);
            }
        }
        __builtin_amdgcn_s_setprio(0);

        // ---- P = exp2(S); inline pack + permlane into PV A-frags ----
        short8 pa[2][2];
#pragma unroll
        for (int mf = 0; mf < 2; mf++) {
#pragma unroll
            for (int kk = 0; kk < 2; kk++) {
                u32x4 wd;
#pragma unroll
                for (int b = 0; b < 2; b++) {
                    float p00 = __builtin_amdgcn_exp2f(sc[2 * kk][mf][2 * b]);
                    float p01 = __builtin_amdgcn_exp2f(sc[2 * kk][mf][2 * b + 1]);
                    float p10 = __builtin_amdgcn_exp2f(sc[2 * kk + 1][mf][2 * b]);
                    float p11 = __builtin_amdgcn_exp2f(sc[2 * kk + 1][mf][2 * b + 1]);
                    unsigned Xw = pk2(p00, p01);
                    unsigned Yw = pk2(p10, p11);
                    uint2v s1 = __builtin_amdgcn_permlane32_swap(Xw, Yw, false, false);
                    uint2v s2 = __builtin_amdgcn_permlane16_swap(s1[0], s1[1], false, false);
                    wd[b]     = s2[0];
                    wd[2 + b] = s2[1];
                }
                pa[mf][kk] = __builtin_bit_cast(short8, wd);
            }
        }

        // ---- O += P V ; lacc += P * ones (row-sum l, free on matrix pipe) ----
        __builtin_amdgcn_s_setprio(1);
#pragma unroll
        for (int kk = 0; kk < 2; kk++) {
            lacc[0] = __builtin_amdgcn_mfma_f32_16x16x32_bf16(pa[0][kk], ones, lacc[0], 0, 0, 0);
            lacc[1] = __builtin_amdgcn_mfma_f32_16x16x32_bf16(pa[1][kk], ones, lacc[1], 0, 0, 0);
#pragma unroll
            for (int np = 0; np < 4; np++) {
                short8 bV = *(const short8*)&vb_[(16 * np + l15) * 72 + kk * 32 + quad * 8];
                o[0][np] = __builtin_amdgcn_mfma_f32_16x16x32_bf16(pa[0][kk], bV, o[0][np], 0, 0, 0);
                o[1][np] = __builtin_amdgcn_mfma_f32_16x16x32_bf16(pa[1][kk], bV, o[1][np], 0, 0, 0);
            }
        }
        __builtin_amdgcn_s_setprio(0);
    }

    // ---- epilogue: write unnormalized partials + row-sums ----
    float* O = half ? O2 : O1;
    float* L = half ? l2 : l1;
    const size_t rowb = (size_t)bh * TT;
#pragma unroll
    for (int mf = 0; mf < 2; mf++) {
#pragma unroll
        for (int reg = 0; reg < 4; reg++) {
            int t = t0 + 32 * w + 16 * mf + quad * 4 + reg;
            if (l15 == 0) L[rowb + t] = lacc[mf][reg];
            float* orow = O + (rowb + t) * DKK;
#pragma unroll
            for (int np = 0; np < 4; np++)
                orow[16 * np + l15] = o[mf][np][reg];
        }
    }
}

// ---------------------------------------------------------------------------
// Split-S combine: Ab[b][t][h][dk] = f2bf((O1+O2) / (l1+l2)).
// grid 2048 x 256 thr; thread handles 8 consecutive dk (f32x4 x2 per half).
// ---------------------------------------------------------------------------
__global__ __launch_bounds__(256)
void combine_norm(const float* __restrict__ O1, const float* __restrict__ O2,
                  const float* __restrict__ l1, const float* __restrict__ l2,
                  short* __restrict__ Ab)
{
    size_t g = (size_t)blockIdx.x * 256 + threadIdx.x;
    size_t i0 = g * 8;
    int bh = (int)(i0 >> 17);          // / (2048*64)
    int t  = (int)((i0 >> 6) & 2047);
    int dk = (int)(i0 & 63);
    float inv = 1.f / (l1[(size_t)bh * TT + t] + l2[(size_t)bh * TT + t]);
    f32x4 a0 = *(const f32x4*)(O1 + i0);
    f32x4 a1 = *(const f32x4*)(O1 + i0 + 4);
    f32x4 b0 = *(const f32x4*)(O2 + i0);
    f32x4 b1 = *(const f32x4*)(O2 + i0 + 4);
    short8 v;
#pragma unroll
    for (int j = 0; j < 4; j++) v[j] = f2bf((a0[j] + b0[j]) * inv);
#pragma unroll
    for (int j = 0; j < 4; j++) v[4 + j] = f2bf((a1[j] + b1[j]) * inv);
    int b = bh >> 4, h = bh & 15;
    *(short8*)(Ab + (((size_t)(b * TT + t) * HH + h) * DKK + dk)) = v;
}

// ---------------------------------------------------------------------------
extern "C" void kernel_launch(void* const* d_in, const int* in_sizes, int n_in,
                              void* d_out, int out_size, void* d_ws, size_t ws_size,
                              hipStream_t stream)
{
    const float* query = (const float*)d_in[0];
    const float* value = (const float*)d_in[1];
    const float* key   = (const float*)d_in[2];
    const float* Wq    = (const float*)d_in[3];
    const float* bq    = (const float*)d_in[4];
    const float* Wk    = (const float*)d_in[5];
    const float* bk    = (const float*)d_in[6];
    const float* Wv    = (const float*)d_in[7];
    const float* bv    = (const float*)d_in[8];
    const float* Wo    = (const float*)d_in[9];
    const float* bo    = (const float*)d_in[10];
    float* out = (float*)d_out;

    const size_t actE = (size_t)MM * DD;    // 4.19M elems
    const size_t wE   = (size_t)DD * NN;    // 1.05M elems
    short* p = (short*)d_ws;
    short* Aq   = p; p += actE;
    short* Ak   = p; p += actE;
    short* Av   = p; p += actE;
    short* Wqt  = p; p += wE;
    short* Wkt  = p; p += wE;
    short* Wvt  = p; p += wE;
    short* Wot  = p; p += wE;
    short* Qb   = p; p += actE;
    short* Kb   = p; p += actE;
    short* Vtmp = p; p += actE;
    short* Vbt  = p; p += actE;
    short* Ab   = p; p += actE;
    float* O2f  = (float*)p; p += 2 * actE;   // 16.8 MB fresh
    // O1/l1/l2 alias the Aq/Ak/Av region (dead after gemm_qkv):
    float* O1f  = (float*)Aq;                 // spans Aq+Ak = exactly actE floats
    float* l1f  = (float*)Av;
    float* l2f  = l1f + (size_t)BB * HH * TT;

    dim3 blk(256);

    // 1. activations fp32 -> bf16
    to_bf16_acts<<<dim3((unsigned)(actE / 2048), 3), blk, 0, stream>>>(
        query, key, value, Aq, Ak, Av);

    // 2. weights fp32 [K][N] -> bf16 [N][K]
    wtrans<<<dim3(16, 16, 4), blk, 0, stream>>>(Wq, Wk, Wv, Wo, Wqt, Wkt, Wvt, Wot);

    // 3. fused QKV projections; all outputs bf16 [bh][t][dk]
    gemm_qkv<<<dim3(NN / 128, MM / 128, 3), blk, 0, stream>>>(
        Aq, Ak, Av, Wqt, Wkt, Wvt, bq, bk, bv, Qb, Kb, Vtmp);

    // 4. V transpose -> [bh][dk][s]
    vtrans<<<dim3(TT / 64, BB * HH), blk, 0, stream>>>(Vtmp, Vbt);

    // 5. flash attention, split-S across z=2 -> f32 partials
    attn_mfma<<<dim3(TT / 128, BB * HH, 2), blk, 0, stream>>>(
        Qb, Kb, Vbt, O1f, O2f, l1f, l2f);

    // 6. combine + normalize -> bf16 Ab
    combine_norm<<<dim3((unsigned)(actE / 2048)), blk, 0, stream>>>(
        O1f, O2f, l1f, l2f, Ab);

    // 7. output projection -> fp32 out
    gemm_out<<<dim3(NN / 128, MM / 64), blk, 0, stream>>>(Ab, Wot, bo, out);
}